// Round 11
// baseline (332.421 us; speedup 1.0000x reference)
//
#include <hip/hip_runtime.h>
#include <hip/hip_bf16.h>
#include <hip/hip_fp8.h>

#define N_NODES 50000
#define M_PAD   50048          // 782 * 64
#define N_EDGES 800000
#define NEG_SLOPE 0.2f

#define SCAN_BLK 256
#define SCAN_NB ((N_NODES + SCAN_BLK - 1) / SCAN_BLK)   // 196
#define SCAT_BLOCKS ((N_EDGES + 255) / 256)              // 3125
#define GEMM1_BLOCKS 1564                                // (M_PAD/64) * (256/128)

typedef __attribute__((ext_vector_type(8))) short bf16x8;
typedef __attribute__((ext_vector_type(4))) float f32x4;
typedef __attribute__((ext_vector_type(2))) float f32x2;

__device__ __forceinline__ unsigned short f2bf(float f) {
    unsigned u = __float_as_uint(f);
    u += 0x7FFFu + ((u >> 16) & 1u);          // RNE
    return (unsigned short)(u >> 16);
}
__device__ __forceinline__ float bf2f(unsigned short h) {
    return __uint_as_float(((unsigned)h) << 16);
}

// ---- fp8 e4m3 HW converts (gfx950 OCP) ----
#if __has_builtin(__builtin_amdgcn_cvt_pk_f32_fp8)
__device__ __forceinline__ f32x2 fp8pk_lo(unsigned int p) { return __builtin_amdgcn_cvt_pk_f32_fp8(p, false); }
__device__ __forceinline__ f32x2 fp8pk_hi(unsigned int p) { return __builtin_amdgcn_cvt_pk_f32_fp8(p, true); }
#else
__device__ __forceinline__ float fp82f_s(unsigned char b) {
    __hip_fp8_e4m3 t; t.__x = (__hip_fp8_storage_t)b; return (float)t;
}
__device__ __forceinline__ f32x2 fp8pk_lo(unsigned int p) {
    f32x2 r; r.x = fp82f_s(p & 0xff); r.y = fp82f_s((p >> 8) & 0xff); return r;
}
__device__ __forceinline__ f32x2 fp8pk_hi(unsigned int p) {
    f32x2 r; r.x = fp82f_s((p >> 16) & 0xff); r.y = fp82f_s(p >> 24); return r;
}
#endif

#if __has_builtin(__builtin_amdgcn_cvt_pk_fp8_f32)
__device__ __forceinline__ unsigned int fp8enc2(float a, float b) {
    return (unsigned int)__builtin_amdgcn_cvt_pk_fp8_f32(a, b, 0, false);
}
#else
__device__ __forceinline__ unsigned int fp8enc2(float a, float b) {
    __hip_fp8_e4m3 ta(a), tb(b);
    return (unsigned int)ta.__x | ((unsigned int)tb.__x << 8);
}
#endif

// ---------------- weights transpose + deg zero ----------------

__global__ __launch_bounds__(256) void k_trans(const float* __restrict__ W1, const float* __restrict__ W2,
                                               const float* __restrict__ resW2,
                                               unsigned short* __restrict__ W1T, unsigned short* __restrict__ W2T,
                                               int* __restrict__ deg) {
    int gtid = (blockIdx.y * 10 + blockIdx.x) * 256 + threadIdx.x;
    for (int i = gtid; i < N_NODES; i += 10 * 8 * 256) deg[i] = 0;

    __shared__ unsigned short tile[32][33];
    int bx = blockIdx.x;
    const float* in;
    unsigned short* out;
    int Nn, n0;
    if (bx < 8)      { in = W1;    out = W1T;            Nn = 256; n0 = bx * 32; }
    else if (bx == 8){ in = W2;    out = W2T;            Nn = 32;  n0 = 0; }
    else             { in = resW2; out = W2T + 32 * 256; Nn = 32;  n0 = 0; }
    int k0 = blockIdx.y * 32;
    int tx = threadIdx.x & 31, ty = threadIdx.x >> 5;  // 32 x 8
    #pragma unroll
    for (int r = 0; r < 4; ++r) {
        int k = k0 + ty + r * 8;
        tile[ty + r * 8][tx] = f2bf(in[(size_t)k * Nn + n0 + tx]);
    }
    __syncthreads();
    #pragma unroll
    for (int r = 0; r < 4; ++r) {
        int n = ty + r * 8;
        out[(size_t)(n0 + n) * 256 + k0 + tx] = tile[tx][n];
    }
}

// ---------------- CSR hist + fused xb cast ----------------

__global__ __launch_bounds__(256) void k_hist(const int* __restrict__ dst, int* __restrict__ deg,
                                              const float* __restrict__ x, unsigned short* __restrict__ xb) {
    int i = blockIdx.x * 256 + threadIdx.x;
    if (i < N_EDGES) atomicAdd(&deg[dst[i]], 1);
    const size_t NCHUNK = (size_t)M_PAD * 256 / 8;
    for (size_t c = (size_t)blockIdx.x * 256 + threadIdx.x; c < NCHUNK; c += (size_t)gridDim.x * 256) {
        size_t base = c * 8;
        float4 a = make_float4(0.f, 0.f, 0.f, 0.f), b = a;
        if (base < (size_t)N_NODES * 256) {
            a = *(const float4*)(x + base);
            b = *(const float4*)(x + base + 4);
        }
        ushort4 h0, h1;
        h0.x = f2bf(a.x); h0.y = f2bf(a.y); h0.z = f2bf(a.z); h0.w = f2bf(a.w);
        h1.x = f2bf(b.x); h1.y = f2bf(b.y); h1.z = f2bf(b.z); h1.w = f2bf(b.w);
        *(ushort4*)(xb + base) = h0;
        *(ushort4*)(xb + base + 4) = h1;
    }
}

// ---------------- scan1 / scan3 ----------------

__global__ __launch_bounds__(SCAN_BLK) void k_scan1(const int* __restrict__ deg,
                                                    int* __restrict__ rowoff,
                                                    int* __restrict__ bsum) {
    __shared__ int s[SCAN_BLK];
    int i = blockIdx.x * SCAN_BLK + threadIdx.x;
    int v = (i < N_NODES) ? deg[i] : 0;
    s[threadIdx.x] = v;
    __syncthreads();
    for (int off = 1; off < SCAN_BLK; off <<= 1) {
        int t = (threadIdx.x >= off) ? s[threadIdx.x - off] : 0;
        __syncthreads();
        s[threadIdx.x] += t;
        __syncthreads();
    }
    if (i < N_NODES) rowoff[i] = s[threadIdx.x];
    if (threadIdx.x == SCAN_BLK - 1) bsum[blockIdx.x] = s[SCAN_BLK - 1];
}

__global__ __launch_bounds__(SCAN_BLK) void k_scan3(const int* __restrict__ deg,
                                                    int* __restrict__ rowoff,
                                                    int* __restrict__ wp,
                                                    const int* __restrict__ bsum) {
    __shared__ int red[4];
    int t = threadIdx.x;
    int part = 0;
    for (int i = t; i < (int)blockIdx.x; i += SCAN_BLK) part += bsum[i];
    #pragma unroll
    for (int m = 1; m <= 32; m <<= 1) part += __shfl_xor(part, m, 64);
    if ((t & 63) == 0) red[t >> 6] = part;
    __syncthreads();
    if (t == 0) red[0] = red[0] + red[1] + red[2] + red[3];
    __syncthreads();
    int off = red[0];
    int i = blockIdx.x * SCAN_BLK + t;
    if (i < N_NODES) {
        int excl = rowoff[i] - deg[i] + off;
        rowoff[i] = excl;
        wp[i] = excl;
    }
    if (i == 0) rowoff[N_NODES] = N_EDGES;
}

// ---------------- MEGA: scatter (blocks 0..3124) || GEMM1+elr1 (blocks 3125..) ----------------
// Scatter is latency-idle (atomics + scattered 4B writes); GEMM is MFMA-dense.
// Co-scheduling lets each fill the other's pipeline bubbles.

__global__ __launch_bounds__(256, 4) void k_mega(const int* __restrict__ src, const int* __restrict__ dst,
                                                 int* __restrict__ wp, int* __restrict__ csr_src,
                                                 const unsigned short* __restrict__ xb,
                                                 const unsigned short* __restrict__ BT,
                                                 const float* __restrict__ al1, const float* __restrict__ ar1,
                                                 unsigned char* __restrict__ Cb8,
                                                 float* __restrict__ el1, float* __restrict__ er1) {
    if (blockIdx.x < SCAT_BLOCKS) {
        int i = blockIdx.x * 256 + threadIdx.x;
        if (i < N_EDGES) {
            int p = atomicAdd(&wp[dst[i]], 1);
            csr_src[p] = src[i];
        }
        return;
    }
    const int g = blockIdx.x - SCAT_BLOCKS;     // 0..1563
    const int t = threadIdx.x;
    const int bm0 = (g % 782) * 64;
    const int bn0 = (g / 782) * 128;
    const int wave = t >> 6, lane = t & 63;
    const int wm = (wave & 1) * 32, wn = (wave >> 1) * 64;
    const int lm = lane & 15, quad = lane >> 4;

    f32x4 acc[2][4];
    #pragma unroll
    for (int i = 0; i < 2; ++i)
        #pragma unroll
        for (int j = 0; j < 4; ++j)
            #pragma unroll
            for (int r = 0; r < 4; ++r) acc[i][j][r] = 0.f;

    const unsigned short* bp[4];
    const unsigned short* ap[2];
    #pragma unroll
    for (int i = 0; i < 4; ++i)
        bp[i] = BT + (size_t)(bn0 + wn + i * 16 + lm) * 256 + quad * 8;
    #pragma unroll
    for (int i = 0; i < 2; ++i)
        ap[i] = xb + (size_t)(bm0 + wm + i * 16 + lm) * 256 + quad * 8;

    // software-pipelined: prefetch next k-tile's fragments during current MFMAs
    bf16x8 nb[4], na[2];
    #pragma unroll
    for (int i = 0; i < 4; ++i) nb[i] = *(const bf16x8*)(bp[i]);
    #pragma unroll
    for (int i = 0; i < 2; ++i) na[i] = *(const bf16x8*)(ap[i]);

    #pragma unroll
    for (int k0 = 0; k0 < 256; k0 += 32) {
        bf16x8 cb[4], ca[2];
        #pragma unroll
        for (int i = 0; i < 4; ++i) cb[i] = nb[i];
        #pragma unroll
        for (int i = 0; i < 2; ++i) ca[i] = na[i];
        if (k0 + 32 < 256) {
            #pragma unroll
            for (int i = 0; i < 4; ++i) nb[i] = *(const bf16x8*)(bp[i] + k0 + 32);
            #pragma unroll
            for (int i = 0; i < 2; ++i) na[i] = *(const bf16x8*)(ap[i] + k0 + 32);
        }
        #pragma unroll
        for (int mi = 0; mi < 2; ++mi)
            #pragma unroll
            for (int ni = 0; ni < 4; ++ni)
                acc[mi][ni] = __builtin_amdgcn_mfma_f32_16x16x32_bf16(ca[mi], cb[ni], acc[mi][ni], 0, 0, 0);
    }

    // store feat1 fp8; C/D layout col=lane&15, row=quad*4+r
    #pragma unroll
    for (int mi = 0; mi < 2; ++mi) {
        #pragma unroll
        for (int ni = 0; ni < 4; ++ni) {
            int col = bn0 + wn + ni * 16 + lm;
            int row0 = bm0 + wm + mi * 16 + quad * 4;
            unsigned int p01 = fp8enc2(acc[mi][ni][0], acc[mi][ni][1]);
            unsigned int p23 = fp8enc2(acc[mi][ni][2], acc[mi][ni][3]);
            Cb8[(size_t)(row0 + 0) * 256 + col] = (unsigned char)(p01 & 0xff);
            Cb8[(size_t)(row0 + 1) * 256 + col] = (unsigned char)((p01 >> 8) & 0xff);
            Cb8[(size_t)(row0 + 2) * 256 + col] = (unsigned char)(p23 & 0xff);
            Cb8[(size_t)(row0 + 3) * 256 + col] = (unsigned char)((p23 >> 8) & 0xff);
        }
    }
    // fused elr1
    float alv[4], arv[4];
    #pragma unroll
    for (int ni = 0; ni < 4; ++ni) {
        int colg = bn0 + wn + ni * 16 + lm;
        alv[ni] = al1[colg];
        arv[ni] = ar1[colg];
    }
    int head0 = (bn0 + wn) >> 5;
    #pragma unroll
    for (int gg = 0; gg < 2; ++gg) {
        #pragma unroll
        for (int mi = 0; mi < 2; ++mi) {
            #pragma unroll
            for (int r = 0; r < 4; ++r) {
                float pel = acc[mi][2 * gg][r] * alv[2 * gg] + acc[mi][2 * gg + 1][r] * alv[2 * gg + 1];
                float per = acc[mi][2 * gg][r] * arv[2 * gg] + acc[mi][2 * gg + 1][r] * arv[2 * gg + 1];
                #pragma unroll
                for (int m = 1; m <= 8; m <<= 1) {
                    pel += __shfl_xor(pel, m, 64);
                    per += __shfl_xor(per, m, 64);
                }
                if (lm == 0) {
                    int row = bm0 + wm + mi * 16 + quad * 4 + r;
                    el1[row * 8 + head0 + gg] = pel;
                    er1[row * 8 + head0 + gg] = per;
                }
            }
        }
    }
}

// ---------------- L1 aggregation: one wave per dst node, packed fp8 decode ----------------

__global__ __launch_bounds__(256) void k_agg1(const unsigned char* __restrict__ feat8,
                                              const float* __restrict__ el1, const float* __restrict__ er1,
                                              const unsigned short* __restrict__ xb, const float* __restrict__ b1,
                                              const int* __restrict__ rowoff, const int* __restrict__ csr_src,
                                              unsigned short* __restrict__ y_b) {
    int v = (blockIdx.x * 256 + threadIdx.x) >> 6;
    int lane = threadIdx.x & 63;
    if (v >= M_PAD) return;
    int c0 = lane * 4;
    if (v >= N_NODES) {
        ushort4 z = {0, 0, 0, 0};
        *(ushort4*)(y_b + (size_t)v * 256 + c0) = z;
        return;
    }
    int h = lane >> 3;
    float er = er1[v * 8 + h];
    float ax = 0.f, ay = 0.f, az = 0.f, aw = 0.f, wsum = 0.f;
    int s = rowoff[v], e = rowoff[v + 1];
    int j = s;
    for (; j + 7 < e; j += 8) {
        int u[8];
        #pragma unroll
        for (int q = 0; q < 8; ++q) u[q] = csr_src[j + q];
        float tt[8];
        #pragma unroll
        for (int q = 0; q < 8; ++q) tt[q] = el1[u[q] * 8 + h] + er;
        unsigned int hv[8];
        #pragma unroll
        for (int q = 0; q < 8; ++q) hv[q] = *(const unsigned int*)(feat8 + (size_t)u[q] * 256 + c0);
        #pragma unroll
        for (int q = 0; q < 8; ++q) {
            float tq = tt[q] > 0.f ? tt[q] : NEG_SLOPE * tt[q];
            float w = __expf(tq);
            wsum += w;
            f32x2 lo = fp8pk_lo(hv[q]);
            f32x2 hi = fp8pk_hi(hv[q]);
            ax += w * lo.x;
            ay += w * lo.y;
            az += w * hi.x;
            aw += w * hi.y;
        }
    }
    for (; j + 3 < e; j += 4) {
        int u[4];
        #pragma unroll
        for (int q = 0; q < 4; ++q) u[q] = csr_src[j + q];
        float tt[4];
        #pragma unroll
        for (int q = 0; q < 4; ++q) tt[q] = el1[u[q] * 8 + h] + er;
        unsigned int hv[4];
        #pragma unroll
        for (int q = 0; q < 4; ++q) hv[q] = *(const unsigned int*)(feat8 + (size_t)u[q] * 256 + c0);
        #pragma unroll
        for (int q = 0; q < 4; ++q) {
            float tq = tt[q] > 0.f ? tt[q] : NEG_SLOPE * tt[q];
            float w = __expf(tq);
            wsum += w;
            f32x2 lo = fp8pk_lo(hv[q]);
            f32x2 hi = fp8pk_hi(hv[q]);
            ax += w * lo.x;
            ay += w * lo.y;
            az += w * hi.x;
            aw += w * hi.y;
        }
    }
    for (; j < e; ++j) {
        int u = csr_src[j];
        float t = el1[u * 8 + h] + er;
        unsigned int hh = *(const unsigned int*)(feat8 + (size_t)u * 256 + c0);
        t = t > 0.f ? t : NEG_SLOPE * t;
        float w = __expf(t);
        wsum += w;
        f32x2 lo = fp8pk_lo(hh);
        f32x2 hi = fp8pk_hi(hh);
        ax += w * lo.x;
        ay += w * lo.y;
        az += w * hi.x;
        aw += w * hi.y;
    }
    float inv = (e > s) ? 1.f / wsum : 0.f;
    ushort4 rh = *(const ushort4*)(xb + (size_t)v * 256 + c0);
    float4 bb = *(const float4*)(b1 + c0);
    ushort4 o;
    o.x = f2bf(fmaxf(ax * inv + bf2f(rh.x) + bb.x, 0.f));
    o.y = f2bf(fmaxf(ay * inv + bf2f(rh.y) + bb.y, 0.f));
    o.z = f2bf(fmaxf(az * inv + bf2f(rh.z) + bb.z, 0.f));
    o.w = f2bf(fmaxf(aw * inv + bf2f(rh.w) + bb.w, 0.f));
    *(ushort4*)(y_b + (size_t)v * 256 + c0) = o;
}

// ---------------- GEMM2 + fused elr2: 64x64 blocks, prefetch pipeline ----------------

__global__ __launch_bounds__(256, 4) void k_gemm2f(const unsigned short* __restrict__ Ab,
                                                   const unsigned short* __restrict__ BT,  // [64][256]
                                                   const float* __restrict__ al2, const float* __restrict__ ar2,
                                                   unsigned short* __restrict__ feat2b, float* __restrict__ res2,
                                                   float* __restrict__ el2, float* __restrict__ er2) {
    const int t = threadIdx.x;
    const int bm0 = blockIdx.x * 64;
    const int wave = t >> 6, lane = t & 63;
    const int wm = (wave & 1) * 32, wn = (wave >> 1) * 32;
    const int lm = lane & 15, quad = lane >> 4;

    f32x4 acc[2][2];
    #pragma unroll
    for (int i = 0; i < 2; ++i)
        #pragma unroll
        for (int j = 0; j < 2; ++j)
            #pragma unroll
            for (int r = 0; r < 4; ++r) acc[i][j][r] = 0.f;

    const unsigned short* bp[2];
    const unsigned short* ap[2];
    #pragma unroll
    for (int i = 0; i < 2; ++i) {
        bp[i] = BT + (size_t)(wn + i * 16 + lm) * 256 + quad * 8;
        ap[i] = Ab + (size_t)(bm0 + wm + i * 16 + lm) * 256 + quad * 8;
    }

    bf16x8 nb[2], na[2];
    #pragma unroll
    for (int i = 0; i < 2; ++i) { nb[i] = *(const bf16x8*)(bp[i]); na[i] = *(const bf16x8*)(ap[i]); }

    #pragma unroll
    for (int k0 = 0; k0 < 256; k0 += 32) {
        bf16x8 cb[2], ca[2];
        #pragma unroll
        for (int i = 0; i < 2; ++i) { cb[i] = nb[i]; ca[i] = na[i]; }
        if (k0 + 32 < 256) {
            #pragma unroll
            for (int i = 0; i < 2; ++i) {
                nb[i] = *(const bf16x8*)(bp[i] + k0 + 32);
                na[i] = *(const bf16x8*)(ap[i] + k0 + 32);
            }
        }
        #pragma unroll
        for (int mi = 0; mi < 2; ++mi)
            #pragma unroll
            for (int ni = 0; ni < 2; ++ni)
                acc[mi][ni] = __builtin_amdgcn_mfma_f32_16x16x32_bf16(ca[mi], cb[ni], acc[mi][ni], 0, 0, 0);
    }

    #pragma unroll
    for (int mi = 0; mi < 2; ++mi) {
        #pragma unroll
        for (int ni = 0; ni < 2; ++ni) {
            int col = wn + ni * 16 + lm;  // 0..63
            #pragma unroll
            for (int r = 0; r < 4; ++r) {
                int row = bm0 + wm + mi * 16 + quad * 4 + r;
                float val = acc[mi][ni][r];
                if (col < 32) feat2b[(size_t)row * 32 + col] = f2bf(val);
                else          res2[(size_t)row * 32 + col - 32] = val;
            }
        }
    }
    if (wn == 0) {
        float alv[2], arv[2];
        #pragma unroll
        for (int ni = 0; ni < 2; ++ni) {
            alv[ni] = al2[ni * 16 + lm];
            arv[ni] = ar2[ni * 16 + lm];
        }
        #pragma unroll
        for (int mi = 0; mi < 2; ++mi) {
            #pragma unroll
            for (int r = 0; r < 4; ++r) {
                float pel = acc[mi][0][r] * alv[0] + acc[mi][1][r] * alv[1];
                float per = acc[mi][0][r] * arv[0] + acc[mi][1][r] * arv[1];
                #pragma unroll
                for (int m = 1; m <= 8; m <<= 1) {
                    pel += __shfl_xor(pel, m, 64);
                    per += __shfl_xor(per, m, 64);
                }
                if (lm == 0) {
                    int row = bm0 + wm + mi * 16 + quad * 4 + r;
                    el2[row] = pel;
                    er2[row] = per;
                }
            }
        }
    }
}

// ---------------- L2 aggregation ----------------

__global__ __launch_bounds__(256) void k_agg2(const unsigned short* __restrict__ feat2b,
                                              const float* __restrict__ el2, const float* __restrict__ er2,
                                              const float* __restrict__ res2, const float* __restrict__ b2,
                                              const int* __restrict__ rowoff, const int* __restrict__ csr_src,
                                              float* __restrict__ out) {
    int g = blockIdx.x * 256 + threadIdx.x;
    int v = g >> 5;
    int c = g & 31;
    if (v >= N_NODES) return;
    float er = er2[v];
    float acc = 0.f, wsum = 0.f;
    int s = rowoff[v], e = rowoff[v + 1];
    int j = s;
    for (; j + 3 < e; j += 4) {
        int u[4];
        #pragma unroll
        for (int q = 0; q < 4; ++q) u[q] = csr_src[j + q];
        float tt[4];
        #pragma unroll
        for (int q = 0; q < 4; ++q) tt[q] = el2[u[q]] + er;
        unsigned short fv[4];
        #pragma unroll
        for (int q = 0; q < 4; ++q) fv[q] = feat2b[(size_t)u[q] * 32 + c];
        #pragma unroll
        for (int q = 0; q < 4; ++q) {
            float tq = tt[q] > 0.f ? tt[q] : NEG_SLOPE * tt[q];
            float w = __expf(tq);
            wsum += w;
            acc += w * bf2f(fv[q]);
        }
    }
    for (; j < e; ++j) {
        int u = csr_src[j];
        float t = el2[u] + er;
        t = t > 0.f ? t : NEG_SLOPE * t;
        float w = __expf(t);
        wsum += w;
        acc += w * bf2f(feat2b[(size_t)u * 32 + c]);
    }
    float inv = (e > s) ? 1.f / wsum : 0.f;
    out[(size_t)v * 32 + c] = acc * inv + res2[(size_t)v * 32 + c] + b2[c];
}

// ---------------- launch ----------------

extern "C" void kernel_launch(void* const* d_in, const int* in_sizes, int n_in,
                              void* d_out, int out_size, void* d_ws, size_t ws_size,
                              hipStream_t stream) {
    const float* x     = (const float*)d_in[0];
    const int*   src   = (const int*)d_in[1];
    const int*   dst   = (const int*)d_in[2];
    const float* W1    = (const float*)d_in[3];
    const float* al1   = (const float*)d_in[4];
    const float* ar1   = (const float*)d_in[5];
    const float* b1    = (const float*)d_in[6];
    const float* W2    = (const float*)d_in[7];
    const float* al2   = (const float*)d_in[8];
    const float* ar2   = (const float*)d_in[9];
    const float* resW2 = (const float*)d_in[10];
    const float* b2    = (const float*)d_in[11];
    float* out = (float*)d_out;

    char* ws = (char*)d_ws;
    size_t off = 0;
    auto alloc = [&](size_t bytes) {
        void* p = ws + off;
        off += (bytes + 255) & ~(size_t)255;
        return p;
    };
    unsigned short* xb     = (unsigned short*)alloc((size_t)M_PAD * 256 * 2);
    unsigned char*  feat8  = (unsigned char*)alloc((size_t)M_PAD * 256);
    unsigned short* y_b    = (unsigned short*)alloc((size_t)M_PAD * 256 * 2);
    unsigned short* W1T    = (unsigned short*)alloc((size_t)256 * 256 * 2);
    unsigned short* W2T    = (unsigned short*)alloc((size_t)64 * 256 * 2);
    unsigned short* feat2b = (unsigned short*)alloc((size_t)M_PAD * 32 * 2);
    float* res2   = (float*)alloc((size_t)M_PAD * 32 * 4);
    float* el1    = (float*)alloc((size_t)M_PAD * 8 * 4);
    float* er1    = (float*)alloc((size_t)M_PAD * 8 * 4);
    float* el2    = (float*)alloc((size_t)M_PAD * 4);
    float* er2    = (float*)alloc((size_t)M_PAD * 4);
    int*   deg    = (int*)alloc((size_t)N_NODES * 4);
    int*   rowoff = (int*)alloc((size_t)(N_NODES + 1) * 4);
    int*   wp     = (int*)alloc((size_t)N_NODES * 4);
    int*   bsum   = (int*)alloc((size_t)SCAN_NB * 4);
    int*   csr    = (int*)alloc((size_t)N_EDGES * 4);
    (void)ws_size;

    // weights transpose + deg zeroing
    k_trans<<<dim3(10, 8), 256, 0, stream>>>(W1, W2, resW2, W1T, W2T, deg);

    // CSR hist + xb cast
    k_hist<<<(N_EDGES + 255) / 256, 256, 0, stream>>>(dst, deg, x, xb);
    k_scan1<<<SCAN_NB, SCAN_BLK, 0, stream>>>(deg, rowoff, bsum);
    k_scan3<<<SCAN_NB, SCAN_BLK, 0, stream>>>(deg, rowoff, wp, bsum);

    // MEGA: scatter || GEMM1(fp8 out)+elr1 — independent work co-scheduled
    k_mega<<<SCAT_BLOCKS + GEMM1_BLOCKS, 256, 0, stream>>>(src, dst, wp, csr,
                                                           xb, W1T, al1, ar1, feat8, el1, er1);

    // Layer 1 aggregation (packed fp8 decode)
    k_agg1<<<(M_PAD * 64) / 256, 256, 0, stream>>>(feat8, el1, er1, xb, b1, rowoff, csr, y_b);

    // Layer 2
    k_gemm2f<<<M_PAD / 64, 256, 0, stream>>>(y_b, W2T, al2, ar2, feat2b, res2, el2, er2);
    k_agg2<<<(N_NODES * 32) / 256, 256, 0, stream>>>(feat2b, el2, er2, res2, b2, rowoff, csr, out);
}

// Round 12
// 303.729 us; speedup vs baseline: 1.0945x; 1.0945x over previous
//
#include <hip/hip_runtime.h>
#include <hip/hip_bf16.h>
#include <hip/hip_fp8.h>

#define N_NODES 50000
#define M_PAD   50048          // 782 * 64
#define N_EDGES 800000
#define NEG_SLOPE 0.2f

#define SCAN_BLK 256
#define SCAN_NB ((N_NODES + SCAN_BLK - 1) / SCAN_BLK)   // 196
#define HIST_BLOCKS 3125
#define GHALF 782
#define MEGA_T (HIST_BLOCKS + GHALF)                     // 3907
#define MEGA_PRIME 1987ull                               // coprime with 3907

typedef __attribute__((ext_vector_type(8))) short bf16x8;
typedef __attribute__((ext_vector_type(4))) float f32x4;
typedef __attribute__((ext_vector_type(2))) float f32x2;

__device__ __forceinline__ unsigned short f2bf(float f) {
    unsigned u = __float_as_uint(f);
    u += 0x7FFFu + ((u >> 16) & 1u);          // RNE
    return (unsigned short)(u >> 16);
}
__device__ __forceinline__ float bf2f(unsigned short h) {
    return __uint_as_float(((unsigned)h) << 16);
}

// ---- fp8 e4m3 HW converts (gfx950 OCP) ----
#if __has_builtin(__builtin_amdgcn_cvt_pk_f32_fp8)
__device__ __forceinline__ f32x2 fp8pk_lo(unsigned int p) { return __builtin_amdgcn_cvt_pk_f32_fp8(p, false); }
__device__ __forceinline__ f32x2 fp8pk_hi(unsigned int p) { return __builtin_amdgcn_cvt_pk_f32_fp8(p, true); }
#else
__device__ __forceinline__ float fp82f_s(unsigned char b) {
    __hip_fp8_e4m3 t; t.__x = (__hip_fp8_storage_t)b; return (float)t;
}
__device__ __forceinline__ f32x2 fp8pk_lo(unsigned int p) {
    f32x2 r; r.x = fp82f_s(p & 0xff); r.y = fp82f_s((p >> 8) & 0xff); return r;
}
__device__ __forceinline__ f32x2 fp8pk_hi(unsigned int p) {
    f32x2 r; r.x = fp82f_s((p >> 16) & 0xff); r.y = fp82f_s(p >> 24); return r;
}
#endif

#if __has_builtin(__builtin_amdgcn_cvt_pk_fp8_f32)
__device__ __forceinline__ unsigned int fp8enc2(float a, float b) {
    return (unsigned int)__builtin_amdgcn_cvt_pk_fp8_f32(a, b, 0, false);
}
#else
__device__ __forceinline__ unsigned int fp8enc2(float a, float b) {
    __hip_fp8_e4m3 ta(a), tb(b);
    return (unsigned int)ta.__x | ((unsigned int)tb.__x << 8);
}
#endif

// ---------------- trans: W transpose + xb cast + deg zero (grid dim3(10,80)) ----------------
// by<8: transpose role (bx picks W1 slice / W2 / resW2). by>=8: xcast role (720 blocks).

__global__ __launch_bounds__(256) void k_trans(const float* __restrict__ W1, const float* __restrict__ W2,
                                               const float* __restrict__ resW2, const float* __restrict__ x,
                                               unsigned short* __restrict__ W1T, unsigned short* __restrict__ W2T,
                                               unsigned short* __restrict__ xb, int* __restrict__ deg) {
    int flat = blockIdx.y * 10 + blockIdx.x;    // 0..799
    for (int i = flat * 256 + threadIdx.x; i < N_NODES; i += 800 * 256) deg[i] = 0;

    if (blockIdx.y < 8) {
        __shared__ unsigned short tile[32][33];
        int bx = blockIdx.x;
        const float* in;
        unsigned short* out;
        int Nn, n0;
        if (bx < 8)      { in = W1;    out = W1T;            Nn = 256; n0 = bx * 32; }
        else if (bx == 8){ in = W2;    out = W2T;            Nn = 32;  n0 = 0; }
        else             { in = resW2; out = W2T + 32 * 256; Nn = 32;  n0 = 0; }
        int k0 = blockIdx.y * 32;
        int tx = threadIdx.x & 31, ty = threadIdx.x >> 5;
        #pragma unroll
        for (int r = 0; r < 4; ++r) {
            int k = k0 + ty + r * 8;
            tile[ty + r * 8][tx] = f2bf(in[(size_t)k * Nn + n0 + tx]);
        }
        __syncthreads();
        #pragma unroll
        for (int r = 0; r < 4; ++r) {
            int n = ty + r * 8;
            out[(size_t)(n0 + n) * 256 + k0 + tx] = tile[tx][n];
        }
    } else {
        int xid = flat - 80;                    // 0..719
        const size_t NCHUNK = (size_t)M_PAD * 256 / 8;
        for (size_t c = (size_t)xid * 256 + threadIdx.x; c < NCHUNK; c += (size_t)720 * 256) {
            size_t base = c * 8;
            float4 a = make_float4(0.f, 0.f, 0.f, 0.f), b = a;
            if (base < (size_t)N_NODES * 256) {
                a = *(const float4*)(x + base);
                b = *(const float4*)(x + base + 4);
            }
            ushort4 h0, h1;
            h0.x = f2bf(a.x); h0.y = f2bf(a.y); h0.z = f2bf(a.z); h0.w = f2bf(a.w);
            h1.x = f2bf(b.x); h1.y = f2bf(b.y); h1.z = f2bf(b.z); h1.w = f2bf(b.w);
            *(ushort4*)(xb + base) = h0;
            *(ushort4*)(xb + base + 4) = h1;
        }
    }
}

// ---------------- shared GEMM1 half body (64-row x 128-col over half the N dim) ----------------

__device__ __forceinline__ void gemm1_half(int g, int bn0,
                                           const unsigned short* __restrict__ xb,
                                           const unsigned short* __restrict__ BT,
                                           const float* __restrict__ al1, const float* __restrict__ ar1,
                                           unsigned char* __restrict__ Cb8,
                                           float* __restrict__ el1, float* __restrict__ er1) {
    const int t = threadIdx.x;
    const int bm0 = g * 64;
    const int wave = t >> 6, lane = t & 63;
    const int wm = (wave & 1) * 32, wn = (wave >> 1) * 64;
    const int lm = lane & 15, quad = lane >> 4;

    f32x4 acc[2][4];
    #pragma unroll
    for (int i = 0; i < 2; ++i)
        #pragma unroll
        for (int j = 0; j < 4; ++j)
            #pragma unroll
            for (int r = 0; r < 4; ++r) acc[i][j][r] = 0.f;

    const unsigned short* bp[4];
    const unsigned short* ap[2];
    #pragma unroll
    for (int i = 0; i < 4; ++i)
        bp[i] = BT + (size_t)(bn0 + wn + i * 16 + lm) * 256 + quad * 8;
    #pragma unroll
    for (int i = 0; i < 2; ++i)
        ap[i] = xb + (size_t)(bm0 + wm + i * 16 + lm) * 256 + quad * 8;

    bf16x8 nb[4], na[2];
    #pragma unroll
    for (int i = 0; i < 4; ++i) nb[i] = *(const bf16x8*)(bp[i]);
    #pragma unroll
    for (int i = 0; i < 2; ++i) na[i] = *(const bf16x8*)(ap[i]);

    #pragma unroll
    for (int k0 = 0; k0 < 256; k0 += 32) {
        bf16x8 cb[4], ca[2];
        #pragma unroll
        for (int i = 0; i < 4; ++i) cb[i] = nb[i];
        #pragma unroll
        for (int i = 0; i < 2; ++i) ca[i] = na[i];
        if (k0 + 32 < 256) {
            #pragma unroll
            for (int i = 0; i < 4; ++i) nb[i] = *(const bf16x8*)(bp[i] + k0 + 32);
            #pragma unroll
            for (int i = 0; i < 2; ++i) na[i] = *(const bf16x8*)(ap[i] + k0 + 32);
        }
        #pragma unroll
        for (int mi = 0; mi < 2; ++mi)
            #pragma unroll
            for (int ni = 0; ni < 4; ++ni)
                acc[mi][ni] = __builtin_amdgcn_mfma_f32_16x16x32_bf16(ca[mi], cb[ni], acc[mi][ni], 0, 0, 0);
    }

    #pragma unroll
    for (int mi = 0; mi < 2; ++mi) {
        #pragma unroll
        for (int ni = 0; ni < 4; ++ni) {
            int col = bn0 + wn + ni * 16 + lm;
            int row0 = bm0 + wm + mi * 16 + quad * 4;
            unsigned int p01 = fp8enc2(acc[mi][ni][0], acc[mi][ni][1]);
            unsigned int p23 = fp8enc2(acc[mi][ni][2], acc[mi][ni][3]);
            Cb8[(size_t)(row0 + 0) * 256 + col] = (unsigned char)(p01 & 0xff);
            Cb8[(size_t)(row0 + 1) * 256 + col] = (unsigned char)((p01 >> 8) & 0xff);
            Cb8[(size_t)(row0 + 2) * 256 + col] = (unsigned char)(p23 & 0xff);
            Cb8[(size_t)(row0 + 3) * 256 + col] = (unsigned char)((p23 >> 8) & 0xff);
        }
    }
    float alv[4], arv[4];
    #pragma unroll
    for (int ni = 0; ni < 4; ++ni) {
        int colg = bn0 + wn + ni * 16 + lm;
        alv[ni] = al1[colg];
        arv[ni] = ar1[colg];
    }
    int head0 = (bn0 + wn) >> 5;
    #pragma unroll
    for (int gg = 0; gg < 2; ++gg) {
        #pragma unroll
        for (int mi = 0; mi < 2; ++mi) {
            #pragma unroll
            for (int r = 0; r < 4; ++r) {
                float pel = acc[mi][2 * gg][r] * alv[2 * gg] + acc[mi][2 * gg + 1][r] * alv[2 * gg + 1];
                float per = acc[mi][2 * gg][r] * arv[2 * gg] + acc[mi][2 * gg + 1][r] * arv[2 * gg + 1];
                #pragma unroll
                for (int m = 1; m <= 8; m <<= 1) {
                    pel += __shfl_xor(pel, m, 64);
                    per += __shfl_xor(per, m, 64);
                }
                if (lm == 0) {
                    int row = bm0 + wm + mi * 16 + quad * 4 + r;
                    el1[row * 8 + head0 + gg] = pel;
                    er1[row * 8 + head0 + gg] = per;
                }
            }
        }
    }
}

// ---------------- MEGA1: hist || GEMM1 cols 0..127 — roles interleaved by prime swizzle ----------------

__global__ __launch_bounds__(256) void k_mega1(const int* __restrict__ dst, int* __restrict__ deg,
                                               const unsigned short* __restrict__ xb,
                                               const unsigned short* __restrict__ BT,
                                               const float* __restrict__ al1, const float* __restrict__ ar1,
                                               unsigned char* __restrict__ Cb8,
                                               float* __restrict__ el1, float* __restrict__ er1) {
    unsigned vb = (unsigned)(((unsigned long long)blockIdx.x * MEGA_PRIME) % MEGA_T);
    if (vb < HIST_BLOCKS) {
        int i = vb * 256 + threadIdx.x;
        if (i < N_EDGES) atomicAdd(&deg[dst[i]], 1);
        return;
    }
    gemm1_half(vb - HIST_BLOCKS, 0, xb, BT, al1, ar1, Cb8, el1, er1);
}

// ---------------- MEGA2: scatter || GEMM1 cols 128..255 ----------------

__global__ __launch_bounds__(256) void k_mega2(const int* __restrict__ src, const int* __restrict__ dst,
                                               int* __restrict__ wp, int* __restrict__ csr_src,
                                               const unsigned short* __restrict__ xb,
                                               const unsigned short* __restrict__ BT,
                                               const float* __restrict__ al1, const float* __restrict__ ar1,
                                               unsigned char* __restrict__ Cb8,
                                               float* __restrict__ el1, float* __restrict__ er1) {
    unsigned vb = (unsigned)(((unsigned long long)blockIdx.x * MEGA_PRIME) % MEGA_T);
    if (vb < HIST_BLOCKS) {
        int i = vb * 256 + threadIdx.x;
        if (i < N_EDGES) {
            int p = atomicAdd(&wp[dst[i]], 1);
            csr_src[p] = src[i];
        }
        return;
    }
    gemm1_half(vb - HIST_BLOCKS, 128, xb, BT, al1, ar1, Cb8, el1, er1);
}

// ---------------- scan1 / scan3 ----------------

__global__ __launch_bounds__(SCAN_BLK) void k_scan1(const int* __restrict__ deg,
                                                    int* __restrict__ rowoff,
                                                    int* __restrict__ bsum) {
    __shared__ int s[SCAN_BLK];
    int i = blockIdx.x * SCAN_BLK + threadIdx.x;
    int v = (i < N_NODES) ? deg[i] : 0;
    s[threadIdx.x] = v;
    __syncthreads();
    for (int off = 1; off < SCAN_BLK; off <<= 1) {
        int t = (threadIdx.x >= off) ? s[threadIdx.x - off] : 0;
        __syncthreads();
        s[threadIdx.x] += t;
        __syncthreads();
    }
    if (i < N_NODES) rowoff[i] = s[threadIdx.x];
    if (threadIdx.x == SCAN_BLK - 1) bsum[blockIdx.x] = s[SCAN_BLK - 1];
}

__global__ __launch_bounds__(SCAN_BLK) void k_scan3(const int* __restrict__ deg,
                                                    int* __restrict__ rowoff,
                                                    int* __restrict__ wp,
                                                    const int* __restrict__ bsum) {
    __shared__ int red[4];
    int t = threadIdx.x;
    int part = 0;
    for (int i = t; i < (int)blockIdx.x; i += SCAN_BLK) part += bsum[i];
    #pragma unroll
    for (int m = 1; m <= 32; m <<= 1) part += __shfl_xor(part, m, 64);
    if ((t & 63) == 0) red[t >> 6] = part;
    __syncthreads();
    if (t == 0) red[0] = red[0] + red[1] + red[2] + red[3];
    __syncthreads();
    int off = red[0];
    int i = blockIdx.x * SCAN_BLK + t;
    if (i < N_NODES) {
        int excl = rowoff[i] - deg[i] + off;
        rowoff[i] = excl;
        wp[i] = excl;
    }
    if (i == 0) rowoff[N_NODES] = N_EDGES;
}

// ---------------- L1 aggregation: one wave per dst node, packed fp8 decode ----------------

__global__ __launch_bounds__(256) void k_agg1(const unsigned char* __restrict__ feat8,
                                              const float* __restrict__ el1, const float* __restrict__ er1,
                                              const unsigned short* __restrict__ xb, const float* __restrict__ b1,
                                              const int* __restrict__ rowoff, const int* __restrict__ csr_src,
                                              unsigned short* __restrict__ y_b) {
    int v = (blockIdx.x * 256 + threadIdx.x) >> 6;
    int lane = threadIdx.x & 63;
    if (v >= M_PAD) return;
    int c0 = lane * 4;
    if (v >= N_NODES) {
        ushort4 z = {0, 0, 0, 0};
        *(ushort4*)(y_b + (size_t)v * 256 + c0) = z;
        return;
    }
    int h = lane >> 3;
    float er = er1[v * 8 + h];
    float ax = 0.f, ay = 0.f, az = 0.f, aw = 0.f, wsum = 0.f;
    int s = rowoff[v], e = rowoff[v + 1];
    int j = s;
    for (; j + 7 < e; j += 8) {
        int u[8];
        #pragma unroll
        for (int q = 0; q < 8; ++q) u[q] = csr_src[j + q];
        float tt[8];
        #pragma unroll
        for (int q = 0; q < 8; ++q) tt[q] = el1[u[q] * 8 + h] + er;
        unsigned int hv[8];
        #pragma unroll
        for (int q = 0; q < 8; ++q) hv[q] = *(const unsigned int*)(feat8 + (size_t)u[q] * 256 + c0);
        #pragma unroll
        for (int q = 0; q < 8; ++q) {
            float tq = tt[q] > 0.f ? tt[q] : NEG_SLOPE * tt[q];
            float w = __expf(tq);
            wsum += w;
            f32x2 lo = fp8pk_lo(hv[q]);
            f32x2 hi = fp8pk_hi(hv[q]);
            ax += w * lo.x;
            ay += w * lo.y;
            az += w * hi.x;
            aw += w * hi.y;
        }
    }
    for (; j + 3 < e; j += 4) {
        int u[4];
        #pragma unroll
        for (int q = 0; q < 4; ++q) u[q] = csr_src[j + q];
        float tt[4];
        #pragma unroll
        for (int q = 0; q < 4; ++q) tt[q] = el1[u[q] * 8 + h] + er;
        unsigned int hv[4];
        #pragma unroll
        for (int q = 0; q < 4; ++q) hv[q] = *(const unsigned int*)(feat8 + (size_t)u[q] * 256 + c0);
        #pragma unroll
        for (int q = 0; q < 4; ++q) {
            float tq = tt[q] > 0.f ? tt[q] : NEG_SLOPE * tt[q];
            float w = __expf(tq);
            wsum += w;
            f32x2 lo = fp8pk_lo(hv[q]);
            f32x2 hi = fp8pk_hi(hv[q]);
            ax += w * lo.x;
            ay += w * lo.y;
            az += w * hi.x;
            aw += w * hi.y;
        }
    }
    for (; j < e; ++j) {
        int u = csr_src[j];
        float t = el1[u * 8 + h] + er;
        unsigned int hh = *(const unsigned int*)(feat8 + (size_t)u * 256 + c0);
        t = t > 0.f ? t : NEG_SLOPE * t;
        float w = __expf(t);
        wsum += w;
        f32x2 lo = fp8pk_lo(hh);
        f32x2 hi = fp8pk_hi(hh);
        ax += w * lo.x;
        ay += w * lo.y;
        az += w * hi.x;
        aw += w * hi.y;
    }
    float inv = (e > s) ? 1.f / wsum : 0.f;
    ushort4 rh = *(const ushort4*)(xb + (size_t)v * 256 + c0);
    float4 bb = *(const float4*)(b1 + c0);
    ushort4 o;
    o.x = f2bf(fmaxf(ax * inv + bf2f(rh.x) + bb.x, 0.f));
    o.y = f2bf(fmaxf(ay * inv + bf2f(rh.y) + bb.y, 0.f));
    o.z = f2bf(fmaxf(az * inv + bf2f(rh.z) + bb.z, 0.f));
    o.w = f2bf(fmaxf(aw * inv + bf2f(rh.w) + bb.w, 0.f));
    *(ushort4*)(y_b + (size_t)v * 256 + c0) = o;
}

// ---------------- GEMM2 + fused elr2: 64x64 blocks, prefetch pipeline ----------------

__global__ __launch_bounds__(256) void k_gemm2f(const unsigned short* __restrict__ Ab,
                                                const unsigned short* __restrict__ BT,  // [64][256]
                                                const float* __restrict__ al2, const float* __restrict__ ar2,
                                                unsigned short* __restrict__ feat2b, float* __restrict__ res2,
                                                float* __restrict__ el2, float* __restrict__ er2) {
    const int t = threadIdx.x;
    const int bm0 = blockIdx.x * 64;
    const int wave = t >> 6, lane = t & 63;
    const int wm = (wave & 1) * 32, wn = (wave >> 1) * 32;
    const int lm = lane & 15, quad = lane >> 4;

    f32x4 acc[2][2];
    #pragma unroll
    for (int i = 0; i < 2; ++i)
        #pragma unroll
        for (int j = 0; j < 2; ++j)
            #pragma unroll
            for (int r = 0; r < 4; ++r) acc[i][j][r] = 0.f;

    const unsigned short* bp[2];
    const unsigned short* ap[2];
    #pragma unroll
    for (int i = 0; i < 2; ++i) {
        bp[i] = BT + (size_t)(wn + i * 16 + lm) * 256 + quad * 8;
        ap[i] = Ab + (size_t)(bm0 + wm + i * 16 + lm) * 256 + quad * 8;
    }

    bf16x8 nb[2], na[2];
    #pragma unroll
    for (int i = 0; i < 2; ++i) { nb[i] = *(const bf16x8*)(bp[i]); na[i] = *(const bf16x8*)(ap[i]); }

    #pragma unroll
    for (int k0 = 0; k0 < 256; k0 += 32) {
        bf16x8 cb[2], ca[2];
        #pragma unroll
        for (int i = 0; i < 2; ++i) { cb[i] = nb[i]; ca[i] = na[i]; }
        if (k0 + 32 < 256) {
            #pragma unroll
            for (int i = 0; i < 2; ++i) {
                nb[i] = *(const bf16x8*)(bp[i] + k0 + 32);
                na[i] = *(const bf16x8*)(ap[i] + k0 + 32);
            }
        }
        #pragma unroll
        for (int mi = 0; mi < 2; ++mi)
            #pragma unroll
            for (int ni = 0; ni < 2; ++ni)
                acc[mi][ni] = __builtin_amdgcn_mfma_f32_16x16x32_bf16(ca[mi], cb[ni], acc[mi][ni], 0, 0, 0);
    }

    #pragma unroll
    for (int mi = 0; mi < 2; ++mi) {
        #pragma unroll
        for (int ni = 0; ni < 2; ++ni) {
            int col = wn + ni * 16 + lm;  // 0..63
            #pragma unroll
            for (int r = 0; r < 4; ++r) {
                int row = bm0 + wm + mi * 16 + quad * 4 + r;
                float val = acc[mi][ni][r];
                if (col < 32) feat2b[(size_t)row * 32 + col] = f2bf(val);
                else          res2[(size_t)row * 32 + col - 32] = val;
            }
        }
    }
    if (wn == 0) {
        float alv[2], arv[2];
        #pragma unroll
        for (int ni = 0; ni < 2; ++ni) {
            alv[ni] = al2[ni * 16 + lm];
            arv[ni] = ar2[ni * 16 + lm];
        }
        #pragma unroll
        for (int mi = 0; mi < 2; ++mi) {
            #pragma unroll
            for (int r = 0; r < 4; ++r) {
                float pel = acc[mi][0][r] * alv[0] + acc[mi][1][r] * alv[1];
                float per = acc[mi][0][r] * arv[0] + acc[mi][1][r] * arv[1];
                #pragma unroll
                for (int m = 1; m <= 8; m <<= 1) {
                    pel += __shfl_xor(pel, m, 64);
                    per += __shfl_xor(per, m, 64);
                }
                if (lm == 0) {
                    int row = bm0 + wm + mi * 16 + quad * 4 + r;
                    el2[row] = pel;
                    er2[row] = per;
                }
            }
        }
    }
}

// ---------------- L2 aggregation ----------------

__global__ __launch_bounds__(256) void k_agg2(const unsigned short* __restrict__ feat2b,
                                              const float* __restrict__ el2, const float* __restrict__ er2,
                                              const float* __restrict__ res2, const float* __restrict__ b2,
                                              const int* __restrict__ rowoff, const int* __restrict__ csr_src,
                                              float* __restrict__ out) {
    int g = blockIdx.x * 256 + threadIdx.x;
    int v = g >> 5;
    int c = g & 31;
    if (v >= N_NODES) return;
    float er = er2[v];
    float acc = 0.f, wsum = 0.f;
    int s = rowoff[v], e = rowoff[v + 1];
    int j = s;
    for (; j + 3 < e; j += 4) {
        int u[4];
        #pragma unroll
        for (int q = 0; q < 4; ++q) u[q] = csr_src[j + q];
        float tt[4];
        #pragma unroll
        for (int q = 0; q < 4; ++q) tt[q] = el2[u[q]] + er;
        unsigned short fv[4];
        #pragma unroll
        for (int q = 0; q < 4; ++q) fv[q] = feat2b[(size_t)u[q] * 32 + c];
        #pragma unroll
        for (int q = 0; q < 4; ++q) {
            float tq = tt[q] > 0.f ? tt[q] : NEG_SLOPE * tt[q];
            float w = __expf(tq);
            wsum += w;
            acc += w * bf2f(fv[q]);
        }
    }
    for (; j < e; ++j) {
        int u = csr_src[j];
        float t = el2[u] + er;
        t = t > 0.f ? t : NEG_SLOPE * t;
        float w = __expf(t);
        wsum += w;
        acc += w * bf2f(feat2b[(size_t)u * 32 + c]);
    }
    float inv = (e > s) ? 1.f / wsum : 0.f;
    out[(size_t)v * 32 + c] = acc * inv + res2[(size_t)v * 32 + c] + b2[c];
}

// ---------------- launch ----------------

extern "C" void kernel_launch(void* const* d_in, const int* in_sizes, int n_in,
                              void* d_out, int out_size, void* d_ws, size_t ws_size,
                              hipStream_t stream) {
    const float* x     = (const float*)d_in[0];
    const int*   src   = (const int*)d_in[1];
    const int*   dst   = (const int*)d_in[2];
    const float* W1    = (const float*)d_in[3];
    const float* al1   = (const float*)d_in[4];
    const float* ar1   = (const float*)d_in[5];
    const float* b1    = (const float*)d_in[6];
    const float* W2    = (const float*)d_in[7];
    const float* al2   = (const float*)d_in[8];
    const float* ar2   = (const float*)d_in[9];
    const float* resW2 = (const float*)d_in[10];
    const float* b2    = (const float*)d_in[11];
    float* out = (float*)d_out;

    char* ws = (char*)d_ws;
    size_t off = 0;
    auto alloc = [&](size_t bytes) {
        void* p = ws + off;
        off += (bytes + 255) & ~(size_t)255;
        return p;
    };
    unsigned short* xb     = (unsigned short*)alloc((size_t)M_PAD * 256 * 2);
    unsigned char*  feat8  = (unsigned char*)alloc((size_t)M_PAD * 256);
    unsigned short* y_b    = (unsigned short*)alloc((size_t)M_PAD * 256 * 2);
    unsigned short* W1T    = (unsigned short*)alloc((size_t)256 * 256 * 2);
    unsigned short* W2T    = (unsigned short*)alloc((size_t)64 * 256 * 2);
    unsigned short* feat2b = (unsigned short*)alloc((size_t)M_PAD * 32 * 2);
    float* res2   = (float*)alloc((size_t)M_PAD * 32 * 4);
    float* el1    = (float*)alloc((size_t)M_PAD * 8 * 4);
    float* er1    = (float*)alloc((size_t)M_PAD * 8 * 4);
    float* el2    = (float*)alloc((size_t)M_PAD * 4);
    float* er2    = (float*)alloc((size_t)M_PAD * 4);
    int*   deg    = (int*)alloc((size_t)N_NODES * 4);
    int*   rowoff = (int*)alloc((size_t)(N_NODES + 1) * 4);
    int*   wp     = (int*)alloc((size_t)N_NODES * 4);
    int*   bsum   = (int*)alloc((size_t)SCAN_NB * 4);
    int*   csr    = (int*)alloc((size_t)N_EDGES * 4);
    (void)ws_size;

    // trans: W transpose + xb cast + deg zero
    k_trans<<<dim3(10, 80), 256, 0, stream>>>(W1, W2, resW2, x, W1T, W2T, xb, deg);

    // MEGA1: hist || gemm1 cols 0..127 (interleaved roles)
    k_mega1<<<MEGA_T, 256, 0, stream>>>(dst, deg, xb, W1T, al1, ar1, feat8, el1, er1);

    k_scan1<<<SCAN_NB, SCAN_BLK, 0, stream>>>(deg, rowoff, bsum);
    k_scan3<<<SCAN_NB, SCAN_BLK, 0, stream>>>(deg, rowoff, wp, bsum);

    // MEGA2: scatter || gemm1 cols 128..255 (interleaved roles)
    k_mega2<<<MEGA_T, 256, 0, stream>>>(src, dst, wp, csr, xb, W1T, al1, ar1, feat8, el1, er1);

    // Layer 1 aggregation (packed fp8 decode)
    k_agg1<<<(M_PAD * 64) / 256, 256, 0, stream>>>(feat8, el1, er1, xb, b1, rowoff, csr, y_b);

    // Layer 2
    k_gemm2f<<<M_PAD / 64, 256, 0, stream>>>(y_b, W2T, al2, ar2, feat2b, res2, el2, er2);
    k_agg2<<<(N_NODES * 32) / 256, 256, 0, stream>>>(feat2b, el2, er2, res2, b2, rowoff, csr, out);
}

// Round 14
// 297.264 us; speedup vs baseline: 1.1183x; 1.0217x over previous
//
#include <hip/hip_runtime.h>
#include <hip/hip_bf16.h>
#include <hip/hip_fp8.h>

#define N_NODES 50000
#define M_PAD   50048          // 782 * 64
#define N_EDGES 800000
#define NEG_SLOPE 0.2f

#define SCAN_BLK 256
#define SCAN_NB ((N_NODES + SCAN_BLK - 1) / SCAN_BLK)   // 196
#define HIST_BLOCKS 3125
#define GHALF 782
#define MEGA_T (HIST_BLOCKS + GHALF)                     // 3907
#define MEGA_PRIME 1987ull                               // coprime with 3907

typedef __attribute__((ext_vector_type(8))) short bf16x8;
typedef __attribute__((ext_vector_type(4))) float f32x4;
typedef __attribute__((ext_vector_type(2))) float f32x2;

__device__ __forceinline__ unsigned short f2bf(float f) {
    unsigned u = __float_as_uint(f);
    u += 0x7FFFu + ((u >> 16) & 1u);          // RNE
    return (unsigned short)(u >> 16);
}
__device__ __forceinline__ float bf2f(unsigned short h) {
    return __uint_as_float(((unsigned)h) << 16);
}

// ---- fp8 e4m3 HW converts (gfx950 OCP) ----
#if __has_builtin(__builtin_amdgcn_cvt_pk_f32_fp8)
__device__ __forceinline__ f32x2 fp8pk_lo(unsigned int p) { return __builtin_amdgcn_cvt_pk_f32_fp8(p, false); }
__device__ __forceinline__ f32x2 fp8pk_hi(unsigned int p) { return __builtin_amdgcn_cvt_pk_f32_fp8(p, true); }
#else
__device__ __forceinline__ float fp82f_s(unsigned char b) {
    __hip_fp8_e4m3 t; t.__x = (__hip_fp8_storage_t)b; return (float)t;
}
__device__ __forceinline__ f32x2 fp8pk_lo(unsigned int p) {
    f32x2 r; r.x = fp82f_s(p & 0xff); r.y = fp82f_s((p >> 8) & 0xff); return r;
}
__device__ __forceinline__ f32x2 fp8pk_hi(unsigned int p) {
    f32x2 r; r.x = fp82f_s((p >> 16) & 0xff); r.y = fp82f_s(p >> 24); return r;
}
#endif

#if __has_builtin(__builtin_amdgcn_cvt_pk_fp8_f32)
__device__ __forceinline__ unsigned int fp8enc2(float a, float b) {
    return (unsigned int)__builtin_amdgcn_cvt_pk_fp8_f32(a, b, 0, false);
}
#else
__device__ __forceinline__ unsigned int fp8enc2(float a, float b) {
    __hip_fp8_e4m3 ta(a), tb(b);
    return (unsigned int)ta.__x | ((unsigned int)tb.__x << 8);
}
#endif

// ---------------- trans: W transpose + xb cast + deg zero (grid dim3(10,80)) ----------------

__global__ __launch_bounds__(256) void k_trans(const float* __restrict__ W1, const float* __restrict__ W2,
                                               const float* __restrict__ resW2, const float* __restrict__ x,
                                               unsigned short* __restrict__ W1T, unsigned short* __restrict__ W2T,
                                               unsigned short* __restrict__ xb, int* __restrict__ deg) {
    int flat = blockIdx.y * 10 + blockIdx.x;    // 0..799
    for (int i = flat * 256 + threadIdx.x; i < N_NODES; i += 800 * 256) deg[i] = 0;

    if (blockIdx.y < 8) {
        __shared__ unsigned short tile[32][33];
        int bx = blockIdx.x;
        const float* in;
        unsigned short* out;
        int Nn, n0;
        if (bx < 8)      { in = W1;    out = W1T;            Nn = 256; n0 = bx * 32; }
        else if (bx == 8){ in = W2;    out = W2T;            Nn = 32;  n0 = 0; }
        else             { in = resW2; out = W2T + 32 * 256; Nn = 32;  n0 = 0; }
        int k0 = blockIdx.y * 32;
        int tx = threadIdx.x & 31, ty = threadIdx.x >> 5;
        #pragma unroll
        for (int r = 0; r < 4; ++r) {
            int k = k0 + ty + r * 8;
            tile[ty + r * 8][tx] = f2bf(in[(size_t)k * Nn + n0 + tx]);
        }
        __syncthreads();
        #pragma unroll
        for (int r = 0; r < 4; ++r) {
            int n = ty + r * 8;
            out[(size_t)(n0 + n) * 256 + k0 + tx] = tile[tx][n];
        }
    } else {
        int xid = flat - 80;                    // 0..719
        const size_t NCHUNK = (size_t)M_PAD * 256 / 8;
        for (size_t c = (size_t)xid * 256 + threadIdx.x; c < NCHUNK; c += (size_t)720 * 256) {
            size_t base = c * 8;
            float4 a = make_float4(0.f, 0.f, 0.f, 0.f), b = a;
            if (base < (size_t)N_NODES * 256) {
                a = *(const float4*)(x + base);
                b = *(const float4*)(x + base + 4);
            }
            ushort4 h0, h1;
            h0.x = f2bf(a.x); h0.y = f2bf(a.y); h0.z = f2bf(a.z); h0.w = f2bf(a.w);
            h1.x = f2bf(b.x); h1.y = f2bf(b.y); h1.z = f2bf(b.z); h1.w = f2bf(b.w);
            *(ushort4*)(xb + base) = h0;
            *(ushort4*)(xb + base + 4) = h1;
        }
    }
}

// ---------------- shared GEMM1 half body (64-row x 128-col over half the N dim) ----------------

__device__ __forceinline__ void gemm1_half(int g, int bn0,
                                           const unsigned short* __restrict__ xb,
                                           const unsigned short* __restrict__ BT,
                                           const float* __restrict__ al1, const float* __restrict__ ar1,
                                           unsigned char* __restrict__ Cb8,
                                           float* __restrict__ el1, float* __restrict__ er1) {
    const int t = threadIdx.x;
    const int bm0 = g * 64;
    const int wave = t >> 6, lane = t & 63;
    const int wm = (wave & 1) * 32, wn = (wave >> 1) * 64;
    const int lm = lane & 15, quad = lane >> 4;

    f32x4 acc[2][4];
    #pragma unroll
    for (int i = 0; i < 2; ++i)
        #pragma unroll
        for (int j = 0; j < 4; ++j)
            #pragma unroll
            for (int r = 0; r < 4; ++r) acc[i][j][r] = 0.f;

    const unsigned short* bp[4];
    const unsigned short* ap[2];
    #pragma unroll
    for (int i = 0; i < 4; ++i)
        bp[i] = BT + (size_t)(bn0 + wn + i * 16 + lm) * 256 + quad * 8;
    #pragma unroll
    for (int i = 0; i < 2; ++i)
        ap[i] = xb + (size_t)(bm0 + wm + i * 16 + lm) * 256 + quad * 8;

    bf16x8 nb[4], na[2];
    #pragma unroll
    for (int i = 0; i < 4; ++i) nb[i] = *(const bf16x8*)(bp[i]);
    #pragma unroll
    for (int i = 0; i < 2; ++i) na[i] = *(const bf16x8*)(ap[i]);

    #pragma unroll
    for (int k0 = 0; k0 < 256; k0 += 32) {
        bf16x8 cb[4], ca[2];
        #pragma unroll
        for (int i = 0; i < 4; ++i) cb[i] = nb[i];
        #pragma unroll
        for (int i = 0; i < 2; ++i) ca[i] = na[i];
        if (k0 + 32 < 256) {
            #pragma unroll
            for (int i = 0; i < 4; ++i) nb[i] = *(const bf16x8*)(bp[i] + k0 + 32);
            #pragma unroll
            for (int i = 0; i < 2; ++i) na[i] = *(const bf16x8*)(ap[i] + k0 + 32);
        }
        #pragma unroll
        for (int mi = 0; mi < 2; ++mi)
            #pragma unroll
            for (int ni = 0; ni < 4; ++ni)
                acc[mi][ni] = __builtin_amdgcn_mfma_f32_16x16x32_bf16(ca[mi], cb[ni], acc[mi][ni], 0, 0, 0);
    }

    #pragma unroll
    for (int mi = 0; mi < 2; ++mi) {
        #pragma unroll
        for (int ni = 0; ni < 4; ++ni) {
            int col = bn0 + wn + ni * 16 + lm;
            int row0 = bm0 + wm + mi * 16 + quad * 4;
            unsigned int p01 = fp8enc2(acc[mi][ni][0], acc[mi][ni][1]);
            unsigned int p23 = fp8enc2(acc[mi][ni][2], acc[mi][ni][3]);
            Cb8[(size_t)(row0 + 0) * 256 + col] = (unsigned char)(p01 & 0xff);
            Cb8[(size_t)(row0 + 1) * 256 + col] = (unsigned char)((p01 >> 8) & 0xff);
            Cb8[(size_t)(row0 + 2) * 256 + col] = (unsigned char)(p23 & 0xff);
            Cb8[(size_t)(row0 + 3) * 256 + col] = (unsigned char)((p23 >> 8) & 0xff);
        }
    }
    float alv[4], arv[4];
    #pragma unroll
    for (int ni = 0; ni < 4; ++ni) {
        int colg = bn0 + wn + ni * 16 + lm;
        alv[ni] = al1[colg];
        arv[ni] = ar1[colg];
    }
    int head0 = (bn0 + wn) >> 5;
    #pragma unroll
    for (int gg = 0; gg < 2; ++gg) {
        #pragma unroll
        for (int mi = 0; mi < 2; ++mi) {
            #pragma unroll
            for (int r = 0; r < 4; ++r) {
                float pel = acc[mi][2 * gg][r] * alv[2 * gg] + acc[mi][2 * gg + 1][r] * alv[2 * gg + 1];
                float per = acc[mi][2 * gg][r] * arv[2 * gg] + acc[mi][2 * gg + 1][r] * arv[2 * gg + 1];
                #pragma unroll
                for (int m = 1; m <= 8; m <<= 1) {
                    pel += __shfl_xor(pel, m, 64);
                    per += __shfl_xor(per, m, 64);
                }
                if (lm == 0) {
                    int row = bm0 + wm + mi * 16 + quad * 4 + r;
                    el1[row * 8 + head0 + gg] = pel;
                    er1[row * 8 + head0 + gg] = per;
                }
            }
        }
    }
}

// ---------------- MEGA1: hist-with-rank || GEMM1 cols 0..127 (prime-swizzled roles) ----------------

__global__ __launch_bounds__(256) void k_mega1(const int* __restrict__ dst, int* __restrict__ deg,
                                               int* __restrict__ rank,
                                               const unsigned short* __restrict__ xb,
                                               const unsigned short* __restrict__ BT,
                                               const float* __restrict__ al1, const float* __restrict__ ar1,
                                               unsigned char* __restrict__ Cb8,
                                               float* __restrict__ el1, float* __restrict__ er1) {
    unsigned vb = (unsigned)(((unsigned long long)blockIdx.x * MEGA_PRIME) % MEGA_T);
    if (vb < HIST_BLOCKS) {
        int i = vb * 256 + threadIdx.x;
        if (i < N_EDGES) rank[i] = atomicAdd(&deg[dst[i]], 1);  // rank capture: scatter needs no atomic
        return;
    }
    gemm1_half(vb - HIST_BLOCKS, 0, xb, BT, al1, ar1, Cb8, el1, er1);
}

// ---------------- MEGA2: atomic-free scatter || GEMM1 cols 128..255 ----------------

__global__ __launch_bounds__(256) void k_mega2(const int* __restrict__ src, const int* __restrict__ dst,
                                               const int* __restrict__ rowoff, const int* __restrict__ rank,
                                               int* __restrict__ csr_src,
                                               const unsigned short* __restrict__ xb,
                                               const unsigned short* __restrict__ BT,
                                               const float* __restrict__ al1, const float* __restrict__ ar1,
                                               unsigned char* __restrict__ Cb8,
                                               float* __restrict__ el1, float* __restrict__ er1) {
    unsigned vb = (unsigned)(((unsigned long long)blockIdx.x * MEGA_PRIME) % MEGA_T);
    if (vb < HIST_BLOCKS) {
        int i = vb * 256 + threadIdx.x;
        if (i < N_EDGES) {
            int d = dst[i];
            csr_src[rowoff[d] + rank[i]] = src[i];
        }
        return;
    }
    gemm1_half(vb - HIST_BLOCKS, 128, xb, BT, al1, ar1, Cb8, el1, er1);
}

// ---------------- scan1 / scan3 ----------------

__global__ __launch_bounds__(SCAN_BLK) void k_scan1(const int* __restrict__ deg,
                                                    int* __restrict__ rowoff,
                                                    int* __restrict__ bsum) {
    __shared__ int s[SCAN_BLK];
    int i = blockIdx.x * SCAN_BLK + threadIdx.x;
    int v = (i < N_NODES) ? deg[i] : 0;
    s[threadIdx.x] = v;
    __syncthreads();
    for (int off = 1; off < SCAN_BLK; off <<= 1) {
        int t = (threadIdx.x >= off) ? s[threadIdx.x - off] : 0;
        __syncthreads();
        s[threadIdx.x] += t;
        __syncthreads();
    }
    if (i < N_NODES) rowoff[i] = s[threadIdx.x];
    if (threadIdx.x == SCAN_BLK - 1) bsum[blockIdx.x] = s[SCAN_BLK - 1];
}

__global__ __launch_bounds__(SCAN_BLK) void k_scan3(const int* __restrict__ deg,
                                                    int* __restrict__ rowoff,
                                                    const int* __restrict__ bsum) {
    __shared__ int red[4];
    int t = threadIdx.x;
    int part = 0;
    for (int i = t; i < (int)blockIdx.x; i += SCAN_BLK) part += bsum[i];
    #pragma unroll
    for (int m = 1; m <= 32; m <<= 1) part += __shfl_xor(part, m, 64);
    if ((t & 63) == 0) red[t >> 6] = part;
    __syncthreads();
    if (t == 0) red[0] = red[0] + red[1] + red[2] + red[3];
    __syncthreads();
    int off = red[0];
    int i = blockIdx.x * SCAN_BLK + t;
    if (i < N_NODES) rowoff[i] = rowoff[i] - deg[i] + off;
    if (i == 0) rowoff[N_NODES] = N_EDGES;
}

// ---------------- L1 aggregation: one wave per dst node, packed fp8 decode ----------------

__global__ __launch_bounds__(256) void k_agg1(const unsigned char* __restrict__ feat8,
                                              const float* __restrict__ el1, const float* __restrict__ er1,
                                              const unsigned short* __restrict__ xb, const float* __restrict__ b1,
                                              const int* __restrict__ rowoff, const int* __restrict__ csr_src,
                                              unsigned short* __restrict__ y_b) {
    int v = (blockIdx.x * 256 + threadIdx.x) >> 6;
    int lane = threadIdx.x & 63;
    if (v >= M_PAD) return;
    int c0 = lane * 4;
    if (v >= N_NODES) {
        ushort4 z = {0, 0, 0, 0};
        *(ushort4*)(y_b + (size_t)v * 256 + c0) = z;
        return;
    }
    int h = lane >> 3;
    float er = er1[v * 8 + h];
    float ax = 0.f, ay = 0.f, az = 0.f, aw = 0.f, wsum = 0.f;
    int s = rowoff[v], e = rowoff[v + 1];
    int j = s;
    for (; j + 7 < e; j += 8) {
        int u[8];
        #pragma unroll
        for (int q = 0; q < 8; ++q) u[q] = csr_src[j + q];
        float tt[8];
        #pragma unroll
        for (int q = 0; q < 8; ++q) tt[q] = el1[u[q] * 8 + h] + er;
        unsigned int hv[8];
        #pragma unroll
        for (int q = 0; q < 8; ++q) hv[q] = *(const unsigned int*)(feat8 + (size_t)u[q] * 256 + c0);
        #pragma unroll
        for (int q = 0; q < 8; ++q) {
            float tq = tt[q] > 0.f ? tt[q] : NEG_SLOPE * tt[q];
            float w = __expf(tq);
            wsum += w;
            f32x2 lo = fp8pk_lo(hv[q]);
            f32x2 hi = fp8pk_hi(hv[q]);
            ax += w * lo.x; ay += w * lo.y; az += w * hi.x; aw += w * hi.y;
        }
    }
    for (; j + 3 < e; j += 4) {
        int u[4];
        #pragma unroll
        for (int q = 0; q < 4; ++q) u[q] = csr_src[j + q];
        float tt[4];
        #pragma unroll
        for (int q = 0; q < 4; ++q) tt[q] = el1[u[q] * 8 + h] + er;
        unsigned int hv[4];
        #pragma unroll
        for (int q = 0; q < 4; ++q) hv[q] = *(const unsigned int*)(feat8 + (size_t)u[q] * 256 + c0);
        #pragma unroll
        for (int q = 0; q < 4; ++q) {
            float tq = tt[q] > 0.f ? tt[q] : NEG_SLOPE * tt[q];
            float w = __expf(tq);
            wsum += w;
            f32x2 lo = fp8pk_lo(hv[q]);
            f32x2 hi = fp8pk_hi(hv[q]);
            ax += w * lo.x; ay += w * lo.y; az += w * hi.x; aw += w * hi.y;
        }
    }
    for (; j < e; ++j) {
        int u = csr_src[j];
        float t = el1[u * 8 + h] + er;
        unsigned int hh = *(const unsigned int*)(feat8 + (size_t)u * 256 + c0);
        t = t > 0.f ? t : NEG_SLOPE * t;
        float w = __expf(t);
        wsum += w;
        f32x2 lo = fp8pk_lo(hh);
        f32x2 hi = fp8pk_hi(hh);
        ax += w * lo.x; ay += w * lo.y; az += w * hi.x; aw += w * hi.y;
    }
    float inv = (e > s) ? 1.f / wsum : 0.f;
    ushort4 rh = *(const ushort4*)(xb + (size_t)v * 256 + c0);
    float4 bb = *(const float4*)(b1 + c0);
    ushort4 o;
    o.x = f2bf(fmaxf(ax * inv + bf2f(rh.x) + bb.x, 0.f));
    o.y = f2bf(fmaxf(ay * inv + bf2f(rh.y) + bb.y, 0.f));
    o.z = f2bf(fmaxf(az * inv + bf2f(rh.z) + bb.z, 0.f));
    o.w = f2bf(fmaxf(aw * inv + bf2f(rh.w) + bb.w, 0.f));
    *(ushort4*)(y_b + (size_t)v * 256 + c0) = o;
}

// ---------------- GEMM2 + fused elr2: 64x64 blocks, prefetch pipeline ----------------

__global__ __launch_bounds__(256) void k_gemm2f(const unsigned short* __restrict__ Ab,
                                                const unsigned short* __restrict__ BT,  // [64][256]
                                                const float* __restrict__ al2, const float* __restrict__ ar2,
                                                unsigned short* __restrict__ feat2b, float* __restrict__ res2,
                                                float* __restrict__ el2, float* __restrict__ er2) {
    const int t = threadIdx.x;
    const int bm0 = blockIdx.x * 64;
    const int wave = t >> 6, lane = t & 63;
    const int wm = (wave & 1) * 32, wn = (wave >> 1) * 32;
    const int lm = lane & 15, quad = lane >> 4;

    f32x4 acc[2][2];
    #pragma unroll
    for (int i = 0; i < 2; ++i)
        #pragma unroll
        for (int j = 0; j < 2; ++j)
            #pragma unroll
            for (int r = 0; r < 4; ++r) acc[i][j][r] = 0.f;

    const unsigned short* bp[2];
    const unsigned short* ap[2];
    #pragma unroll
    for (int i = 0; i < 2; ++i) {
        bp[i] = BT + (size_t)(wn + i * 16 + lm) * 256 + quad * 8;
        ap[i] = Ab + (size_t)(bm0 + wm + i * 16 + lm) * 256 + quad * 8;
    }

    bf16x8 nb[2], na[2];
    #pragma unroll
    for (int i = 0; i < 2; ++i) { nb[i] = *(const bf16x8*)(bp[i]); na[i] = *(const bf16x8*)(ap[i]); }

    #pragma unroll
    for (int k0 = 0; k0 < 256; k0 += 32) {
        bf16x8 cb[2], ca[2];
        #pragma unroll
        for (int i = 0; i < 2; ++i) { cb[i] = nb[i]; ca[i] = na[i]; }
        if (k0 + 32 < 256) {
            #pragma unroll
            for (int i = 0; i < 2; ++i) {
                nb[i] = *(const bf16x8*)(bp[i] + k0 + 32);
                na[i] = *(const bf16x8*)(ap[i] + k0 + 32);
            }
        }
        #pragma unroll
        for (int mi = 0; mi < 2; ++mi)
            #pragma unroll
            for (int ni = 0; ni < 2; ++ni)
                acc[mi][ni] = __builtin_amdgcn_mfma_f32_16x16x32_bf16(ca[mi], cb[ni], acc[mi][ni], 0, 0, 0);
    }

    #pragma unroll
    for (int mi = 0; mi < 2; ++mi) {
        #pragma unroll
        for (int ni = 0; ni < 2; ++ni) {
            int col = wn + ni * 16 + lm;  // 0..63
            #pragma unroll
            for (int r = 0; r < 4; ++r) {
                int row = bm0 + wm + mi * 16 + quad * 4 + r;
                float val = acc[mi][ni][r];
                if (col < 32) feat2b[(size_t)row * 32 + col] = f2bf(val);
                else          res2[(size_t)row * 32 + col - 32] = val;
            }
        }
    }
    if (wn == 0) {
        float alv[2], arv[2];
        #pragma unroll
        for (int ni = 0; ni < 2; ++ni) {
            alv[ni] = al2[ni * 16 + lm];
            arv[ni] = ar2[ni * 16 + lm];
        }
        #pragma unroll
        for (int mi = 0; mi < 2; ++mi) {
            #pragma unroll
            for (int r = 0; r < 4; ++r) {
                float pel = acc[mi][0][r] * alv[0] + acc[mi][1][r] * alv[1];
                float per = acc[mi][0][r] * arv[0] + acc[mi][1][r] * arv[1];
                #pragma unroll
                for (int m = 1; m <= 8; m <<= 1) {
                    pel += __shfl_xor(pel, m, 64);
                    per += __shfl_xor(per, m, 64);
                }
                if (lm == 0) {
                    int row = bm0 + wm + mi * 16 + quad * 4 + r;
                    el2[row] = pel;
                    er2[row] = per;
                }
            }
        }
    }
}

// ---------------- L2 aggregation ----------------

__global__ __launch_bounds__(256) void k_agg2(const unsigned short* __restrict__ feat2b,
                                              const float* __restrict__ el2, const float* __restrict__ er2,
                                              const float* __restrict__ res2, const float* __restrict__ b2,
                                              const int* __restrict__ rowoff, const int* __restrict__ csr_src,
                                              float* __restrict__ out) {
    int g = blockIdx.x * 256 + threadIdx.x;
    int v = g >> 5;
    int c = g & 31;
    if (v >= N_NODES) return;
    float er = er2[v];
    float acc = 0.f, wsum = 0.f;
    int s = rowoff[v], e = rowoff[v + 1];
    int j = s;
    for (; j + 3 < e; j += 4) {
        int u[4];
        #pragma unroll
        for (int q = 0; q < 4; ++q) u[q] = csr_src[j + q];
        float tt[4];
        #pragma unroll
        for (int q = 0; q < 4; ++q) tt[q] = el2[u[q]] + er;
        unsigned short fv[4];
        #pragma unroll
        for (int q = 0; q < 4; ++q) fv[q] = feat2b[(size_t)u[q] * 32 + c];
        #pragma unroll
        for (int q = 0; q < 4; ++q) {
            float tq = tt[q] > 0.f ? tt[q] : NEG_SLOPE * tt[q];
            float w = __expf(tq);
            wsum += w;
            acc += w * bf2f(fv[q]);
        }
    }
    for (; j < e; ++j) {
        int u = csr_src[j];
        float t = el2[u] + er;
        t = t > 0.f ? t : NEG_SLOPE * t;
        float w = __expf(t);
        wsum += w;
        acc += w * bf2f(feat2b[(size_t)u * 32 + c]);
    }
    float inv = (e > s) ? 1.f / wsum : 0.f;
    out[(size_t)v * 32 + c] = acc * inv + res2[(size_t)v * 32 + c] + b2[c];
}

// ---------------- launch ----------------

extern "C" void kernel_launch(void* const* d_in, const int* in_sizes, int n_in,
                              void* d_out, int out_size, void* d_ws, size_t ws_size,
                              hipStream_t stream) {
    const float* x     = (const float*)d_in[0];
    const int*   src   = (const int*)d_in[1];
    const int*   dst   = (const int*)d_in[2];
    const float* W1    = (const float*)d_in[3];
    const float* al1   = (const float*)d_in[4];
    const float* ar1   = (const float*)d_in[5];
    const float* b1    = (const float*)d_in[6];
    const float* W2    = (const float*)d_in[7];
    const float* al2   = (const float*)d_in[8];
    const float* ar2   = (const float*)d_in[9];
    const float* resW2 = (const float*)d_in[10];
    const float* b2    = (const float*)d_in[11];
    float* out = (float*)d_out;

    char* ws = (char*)d_ws;
    size_t off = 0;
    auto alloc = [&](size_t bytes) {
        void* p = ws + off;
        off += (bytes + 255) & ~(size_t)255;
        return p;
    };
    unsigned short* xb     = (unsigned short*)alloc((size_t)M_PAD * 256 * 2);
    unsigned char*  feat8  = (unsigned char*)alloc((size_t)M_PAD * 256);
    unsigned short* y_b    = (unsigned short*)alloc((size_t)M_PAD * 256 * 2);
    unsigned short* W1T    = (unsigned short*)alloc((size_t)256 * 256 * 2);
    unsigned short* W2T    = (unsigned short*)alloc((size_t)64 * 256 * 2);
    unsigned short* feat2b = (unsigned short*)alloc((size_t)M_PAD * 32 * 2);
    float* res2   = (float*)alloc((size_t)M_PAD * 32 * 4);
    float* el1    = (float*)alloc((size_t)M_PAD * 8 * 4);
    float* er1    = (float*)alloc((size_t)M_PAD * 8 * 4);
    float* el2    = (float*)alloc((size_t)M_PAD * 4);
    float* er2    = (float*)alloc((size_t)M_PAD * 4);
    int*   deg    = (int*)alloc((size_t)N_NODES * 4);
    int*   rank   = (int*)alloc((size_t)N_EDGES * 4);
    int*   rowoff = (int*)alloc((size_t)(N_NODES + 1) * 4);
    int*   bsum   = (int*)alloc((size_t)SCAN_NB * 4);
    int*   csr    = (int*)alloc((size_t)N_EDGES * 4);
    (void)ws_size;

    // trans: W transpose + xb cast + deg zero
    k_trans<<<dim3(10, 80), 256, 0, stream>>>(W1, W2, resW2, x, W1T, W2T, xb, deg);

    // MEGA1: hist-with-rank || gemm1 cols 0..127
    k_mega1<<<MEGA_T, 256, 0, stream>>>(dst, deg, rank, xb, W1T, al1, ar1, feat8, el1, er1);

    k_scan1<<<SCAN_NB, SCAN_BLK, 0, stream>>>(deg, rowoff, bsum);
    k_scan3<<<SCAN_NB, SCAN_BLK, 0, stream>>>(deg, rowoff, bsum);

    // MEGA2: atomic-free scatter || gemm1 cols 128..255
    k_mega2<<<MEGA_T, 256, 0, stream>>>(src, dst, rowoff, rank, csr, xb, W1T, al1, ar1, feat8, el1, er1);

    // Layer 1 aggregation (packed fp8 decode)
    k_agg1<<<(M_PAD * 64) / 256, 256, 0, stream>>>(feat8, el1, er1, xb, b1, rowoff, csr, y_b);

    // Layer 2
    k_gemm2f<<<M_PAD / 64, 256, 0, stream>>>(y_b, W2T, al2, ar2, feat2b, res2, el2, er2);
    k_agg2<<<(N_NODES * 32) / 256, 256, 0, stream>>>(feat2b, el2, er2, res2, b2, rowoff, csr, out);
}